// Round 3
// baseline (1179.818 us; speedup 1.0000x reference)
//
#include <hip/hip_runtime.h>

// ---- problem constants ----
#define NB    16
#define DIM   512
#define HH    56
#define WW    56
#define HWPIX 3136
#define HID   2048
#define NSTYLE 64
#define NLAT   8

typedef float f32x4 __attribute__((ext_vector_type(4)));
typedef __bf16 bf16x8 __attribute__((ext_vector_type(8)));
typedef unsigned short u16x8 __attribute__((ext_vector_type(8)));

__device__ __forceinline__ unsigned short f2bf(float f) {
  unsigned u = __float_as_uint(f);
  u += 0x7fffu + ((u >> 16) & 1u);   // round-to-nearest-even
  return (unsigned short)(u >> 16);
}

__device__ __forceinline__ void gload16(const void* g, void* l) {
  __builtin_amdgcn_global_load_lds((__attribute__((address_space(1))) void*)g,
                                   (__attribute__((address_space(3))) void*)l,
                                   16, 0, 0);
}

// ---- 1. small per-sample vectors: z_dw/z1/z2 [B,8], b_dw [B,512], b1 [B,2048], b2 [B,512] ----
__global__ __launch_bounds__(256)
void k_small(const float* __restrict__ s,
             const float* __restrict__ dw_fc_w, const float* __restrict__ dw_fc_b,
             const float* __restrict__ dw_bfc_w, const float* __restrict__ dw_bfc_b,
             const float* __restrict__ p1_fc_w, const float* __restrict__ p1_fc_b,
             const float* __restrict__ p1_bfc_w, const float* __restrict__ p1_bfc_b,
             const float* __restrict__ p2_fc_w, const float* __restrict__ p2_fc_b,
             const float* __restrict__ p2_bfc_w, const float* __restrict__ p2_bfc_b,
             float* __restrict__ z_dw, float* __restrict__ z1, float* __restrict__ z2,
             float* __restrict__ b_dw, float* __restrict__ b1, float* __restrict__ b2) {
  int b = blockIdx.x, t = threadIdx.x;
  __shared__ float ls[NSTYLE];
  if (t < NSTYLE) ls[t] = s[b*NSTYLE + t];
  __syncthreads();
  if (t < NLAT) {
    float a0 = dw_fc_b[t], a1 = p1_fc_b[t], a2 = p2_fc_b[t];
    for (int j = 0; j < NSTYLE; ++j) {
      float sv = ls[j];
      a0 += sv * dw_fc_w[j*NLAT + t];
      a1 += sv * p1_fc_w[j*NLAT + t];
      a2 += sv * p2_fc_w[j*NLAT + t];
    }
    z_dw[b*NLAT + t] = a0; z1[b*NLAT + t] = a1; z2[b*NLAT + t] = a2;
  }
  for (int c = t; c < DIM; c += 256) {
    float a = dw_bfc_b[c], a2 = p2_bfc_b[c];
    for (int j = 0; j < NSTYLE; ++j) {
      float sv = ls[j];
      a  += sv * dw_bfc_w[j*DIM + c];
      a2 += sv * p2_bfc_w[j*DIM + c];
    }
    b_dw[b*DIM + c] = a; b2[b*DIM + c] = a2;
  }
  for (int c = t; c < HID; c += 256) {
    float a = p1_bfc_b[c];
    for (int j = 0; j < NSTYLE; ++j) a += ls[j] * p1_bfc_w[j*HID + c];
    b1[b*HID + c] = a;
  }
}

// ---- 2. depthwise kernel weights: wdw[b,c,49] = sum_l z_dw[b,l]*dw_param[l,c,49] ----
__global__ __launch_bounds__(256)
void k_wdw(const float* __restrict__ z_dw, const float* __restrict__ dw_param,
           float* __restrict__ wdw) {
  int idx = blockIdx.x * 256 + threadIdx.x;
  if (idx >= NB*DIM) return;
  int b = idx >> 9, c = idx & 511;
  float z[NLAT];
#pragma unroll
  for (int ll = 0; ll < NLAT; ++ll) z[ll] = z_dw[b*NLAT + ll];
  for (int k = 0; k < 49; ++k) {
    float a = 0.f;
#pragma unroll
    for (int ll = 0; ll < NLAT; ++ll) a += z[ll] * dw_param[((long)ll*DIM + c)*49 + k];
    wdw[(long)idx*49 + k] = a;
  }
}

// ---- 3. generated GEMM weights (bf16, K-contiguous): out[b][e] = sum_l z[b,l]*param[l][e] ----
__global__ __launch_bounds__(256)
void k_wgen(const float* __restrict__ z, const float* __restrict__ param,
            unsigned short* __restrict__ out, long OI) {
  __shared__ float lz[NB*NLAT];
  if (threadIdx.x < NB*NLAT) lz[threadIdx.x] = z[threadIdx.x];
  __syncthreads();
  long e4 = ((long)blockIdx.x * 256 + threadIdx.x) * 4;
  if (e4 >= OI) return;
  float a[NB][4] = {};
#pragma unroll
  for (int ll = 0; ll < NLAT; ++ll) {
    float4 v = *(const float4*)(param + (long)ll*OI + e4);
#pragma unroll
    for (int b = 0; b < NB; ++b) {
      float zz = lz[b*NLAT + ll];
      a[b][0] += zz*v.x; a[b][1] += zz*v.y; a[b][2] += zz*v.z; a[b][3] += zz*v.w;
    }
  }
#pragma unroll
  for (int b = 0; b < NB; ++b) {
    ushort4 pk;
    pk.x = f2bf(a[b][0]); pk.y = f2bf(a[b][1]); pk.z = f2bf(a[b][2]); pk.w = f2bf(a[b][3]);
    *(ushort4*)(out + (long)b*OI + e4) = pk;
  }
}

// ---- 4. depthwise 7x7 conv with on-the-fly reflection pad; 1 wave per (b,c) plane ----
__global__ __launch_bounds__(64)
void k_dwconv(const float* __restrict__ x, const float* __restrict__ wdw,
              const float* __restrict__ bdw, float* __restrict__ y) {
  int bc = blockIdx.x;
  const float* xb = x + (long)bc * HWPIX;
  float* yb = y + (long)bc * HWPIX;
  int ox = threadIdx.x;
  bool act = ox < WW;
  int oxc = act ? ox : WW-1;
  int cj[7];
#pragma unroll
  for (int j = 0; j < 7; ++j) {
    int v = oxc + j - 3;
    v = v < 0 ? -v : (v > WW-1 ? 2*(WW-1) - v : v);
    cj[j] = v;
  }
  float wk[49];
#pragma unroll
  for (int k = 0; k < 49; ++k) wk[k] = wdw[(long)bc*49 + k];   // uniform -> scalar loads
  float bias = bdw[bc];
  float acc[7];
#pragma unroll
  for (int j = 0; j < 7; ++j) acc[j] = bias;
#pragma unroll 62
  for (int r = 0; r < HH + 6; ++r) {
    int sy = r - 3;
    sy = sy < 0 ? -sy : (sy > HH-1 ? 2*(HH-1) - sy : sy);
    const float* rowp = xb + sy*WW;
    float v[7];
#pragma unroll
    for (int j = 0; j < 7; ++j) v[j] = rowp[cj[j]];
#pragma unroll
    for (int dy = 0; dy < 7; ++dy) {
      int orow = r - dy;
      if (orow >= 0 && orow < HH) {
        float a = acc[orow % 7];
#pragma unroll
        for (int dx = 0; dx < 7; ++dx) a += v[dx] * wk[dy*7 + dx];
        acc[orow % 7] = a;
      }
    }
    if (r >= 6) {
      int orow = r - 6;
      if (act) yb[orow*WW + oxc] = acc[orow % 7];
      acc[orow % 7] = bias;
    }
  }
}

// ---- 5. channels-first LayerNorm -> pixel-major bf16 activation [B, 3136, 512] ----
__global__ __launch_bounds__(256)
void k_ln(const float* __restrict__ y, const float* __restrict__ ln_w,
          const float* __restrict__ ln_b, unsigned short* __restrict__ xln) {
  int b = blockIdx.y;
  int p = blockIdx.x * 256 + threadIdx.x;
  if (p >= HWPIX) return;
  const float* yb = y + (long)b * DIM * HWPIX;
  float s = 0.f, s2 = 0.f;
  for (int c = 0; c < DIM; ++c) {
    float v = yb[(long)c*HWPIX + p];
    s += v; s2 += v*v;
  }
  float mean = s * (1.0f/DIM);
  float var  = s2 * (1.0f/DIM) - mean*mean;
  float rstd = rsqrtf(var + 1e-6f);
  unsigned short* dst = xln + ((long)b*HWPIX + p) * DIM;
  for (int c0 = 0; c0 < DIM; c0 += 8) {
    u16x8 pk;
#pragma unroll
    for (int j = 0; j < 8; ++j) {
      int c = c0 + j;
      float v = (yb[(long)c*HWPIX + p] - mean) * rstd * ln_w[c] + ln_b[c];
      pk[j] = f2bf(v);
    }
    *(u16x8*)(dst + c0) = pk;
  }
}

// ---- 6. MFMA GEMM, 128x128 tile, BK=32, m97-style global_load_lds staging ----
// D[row][col] = sum_k A[row][k]*Bt[col][k]   (A,Bt bf16 K-contiguous)
// MODE 1: + bias[col], exact GELU, store bf16 (h, pixel-major)
// MODE 2: (D + bias[row]) * gamma[row] + xin, store f32 (final NCHW)
template<int MODE>
__global__ __launch_bounds__(256)
void k_gemm(const unsigned short* __restrict__ A, const unsigned short* __restrict__ Bt,
            const float* __restrict__ bias,
            unsigned short* __restrict__ hout,
            const float* __restrict__ xin, const float* __restrict__ gamma,
            float* __restrict__ fout,
            int M, int N, int Kd, long sA, long sBt, int sBias) {
  __shared__ unsigned short lsA[128*32];
  __shared__ unsigned short lsB[128*32];
  int bz = blockIdx.z;
  int row0 = blockIdx.y * 128, col0 = blockIdx.x * 128;
  int t = threadIdx.x, l = t & 63, w = t >> 6;
  const unsigned short* Ab  = A  + (long)bz * sA;
  const unsigned short* Btb = Bt + (long)bz * sBt;
  int srow = w*32 + (l >> 2);        // staging row within tile (this wave covers 32 rows)
  int skb  = (l & 3) * 8;            // staging k-offset (elements)
  const unsigned short* ga = Ab  + (long)(row0 + srow) * Kd + skb;
  const unsigned short* gb = Btb + (long)(col0 + srow) * Kd + skb;
  unsigned short* la = &lsA[srow*32 + skb];   // == wave_base + lane*16B (linear)
  unsigned short* lb = &lsB[srow*32 + skb];
  int wr = w >> 1, wc = w & 1;
  int rr = l & 15, kg = (l >> 4) * 8;
  f32x4 acc[4][4] = {};
  int nk = Kd >> 5;
  for (int kk = 0; kk < nk; ++kk) {
    gload16(ga, la);
    gload16(ga + 16*(long)Kd, la + 16*32);
    gload16(gb, lb);
    gload16(gb + 16*(long)Kd, lb + 16*32);
    ga += 32; gb += 32;
    __syncthreads();                 // compiler drains vmcnt(0) before barrier
    bf16x8 af[4], bfr[4];
#pragma unroll
    for (int m = 0; m < 4; ++m)
      af[m] = *(const bf16x8*)&lsA[(wr*64 + m*16 + rr)*32 + kg];
#pragma unroll
    for (int n = 0; n < 4; ++n)
      bfr[n] = *(const bf16x8*)&lsB[(wc*64 + n*16 + rr)*32 + kg];
#pragma unroll
    for (int m = 0; m < 4; ++m)
#pragma unroll
      for (int n = 0; n < 4; ++n)
        acc[m][n] = __builtin_amdgcn_mfma_f32_16x16x32_bf16(af[m], bfr[n], acc[m][n], 0, 0, 0);
    __syncthreads();
  }
  long ob = (long)bz * M * N;
  const float* biasb = bias + (long)bz * sBias;
#pragma unroll
  for (int m = 0; m < 4; ++m) {
#pragma unroll
    for (int n = 0; n < 4; ++n) {
      int col = col0 + wc*64 + n*16 + rr;
#pragma unroll
      for (int j = 0; j < 4; ++j) {
        int row = row0 + wr*64 + m*16 + (l >> 4)*4 + j;   // C/D: col=lane&15, row=(lane>>4)*4+reg
        float v = acc[m][n][j];
        if constexpr (MODE == 1) {
          if (row < M) {
            v += biasb[col];
            v = 0.5f * v * (1.0f + erff(v * 0.70710678118654752f));
            hout[ob + (long)row * N + col] = f2bf(v);
          }
        } else {
          if (col < N) {
            v = (v + biasb[row]) * gamma[row] + xin[ob + (long)row * N + col];
            fout[ob + (long)row * N + col] = v;
          }
        }
      }
    }
  }
}

extern "C" void kernel_launch(void* const* d_in, const int* in_sizes, int n_in,
                              void* d_out, int out_size, void* d_ws, size_t ws_size,
                              hipStream_t stream) {
  (void)in_sizes; (void)n_in; (void)out_size; (void)ws_size;
  const float* x         = (const float*)d_in[0];
  const float* s         = (const float*)d_in[1];
  const float* dw_fc_w   = (const float*)d_in[2];
  const float* dw_fc_b   = (const float*)d_in[3];
  const float* dw_param  = (const float*)d_in[4];
  const float* dw_bfc_w  = (const float*)d_in[5];
  const float* dw_bfc_b  = (const float*)d_in[6];
  const float* ln_w      = (const float*)d_in[7];
  const float* ln_b      = (const float*)d_in[8];
  const float* pw1_fc_w  = (const float*)d_in[9];
  const float* pw1_fc_b  = (const float*)d_in[10];
  const float* pw1_param = (const float*)d_in[11];
  const float* pw1_bfc_w = (const float*)d_in[12];
  const float* pw1_bfc_b = (const float*)d_in[13];
  const float* pw2_fc_w  = (const float*)d_in[14];
  const float* pw2_fc_b  = (const float*)d_in[15];
  const float* pw2_param = (const float*)d_in[16];
  const float* pw2_bfc_w = (const float*)d_in[17];
  const float* pw2_bfc_b = (const float*)d_in[18];
  const float* gamma     = (const float*)d_in[19];
  float* out = (float*)d_out;

  char* ws = (char*)d_ws;
  size_t off = 0;
  auto alloc = [&](size_t bytes) {
    void* p = ws + off;
    off += (bytes + 255) & ~(size_t)255;
    return p;
  };
  float* z_dw = (float*)alloc(NB*NLAT*4);
  float* z1   = (float*)alloc(NB*NLAT*4);
  float* z2   = (float*)alloc(NB*NLAT*4);
  float* b_dw = (float*)alloc((size_t)NB*DIM*4);
  float* b2   = (float*)alloc((size_t)NB*DIM*4);
  float* b1   = (float*)alloc((size_t)NB*HID*4);
  float* wdw  = (float*)alloc((size_t)NB*DIM*49*4);
  unsigned short* w1  = (unsigned short*)alloc((size_t)NB*HID*DIM*2);
  unsigned short* w2  = (unsigned short*)alloc((size_t)NB*DIM*HID*2);
  unsigned short* xln = (unsigned short*)alloc((size_t)NB*HWPIX*DIM*2 + 131072);  // + edge-tile pad
  unsigned short* h   = (unsigned short*)alloc((size_t)NB*HWPIX*HID*2 + 524288);  // + edge-tile pad

  float* y = out;  // reuse d_out as dwconv scratch; fully overwritten by final GEMM

  k_small<<<NB, 256, 0, stream>>>(s, dw_fc_w, dw_fc_b, dw_bfc_w, dw_bfc_b,
                                  pw1_fc_w, pw1_fc_b, pw1_bfc_w, pw1_bfc_b,
                                  pw2_fc_w, pw2_fc_b, pw2_bfc_w, pw2_bfc_b,
                                  z_dw, z1, z2, b_dw, b1, b2);
  k_wdw<<<(NB*DIM + 255)/256, 256, 0, stream>>>(z_dw, dw_param, wdw);
  {
    long OI = (long)HID * DIM;                  // 1,048,576
    int blocks = (int)(OI / 4 / 256);           // 1024, exact
    k_wgen<<<blocks, 256, 0, stream>>>(z1, pw1_param, w1, OI);
    k_wgen<<<blocks, 256, 0, stream>>>(z2, pw2_param, w2, OI);
  }
  k_dwconv<<<NB*DIM, 64, 0, stream>>>(x, wdw, b_dw, y);
  k_ln<<<dim3((HWPIX + 255)/256, NB), 256, 0, stream>>>(y, ln_w, ln_b, xln);

  // GEMM1: h[p][o] = GELU( xln[p][:] . w1[o][:] + b1[o] ),  M=3136, N=2048, K=512
  k_gemm<1><<<dim3(HID/128, (HWPIX + 127)/128, NB), 256, 0, stream>>>(
      xln, w1, b1, h, nullptr, nullptr, nullptr,
      HWPIX, HID, DIM, (long)HWPIX*DIM, (long)HID*DIM, HID);

  // GEMM2: out[c][p] = xin + gamma[c] * ( w2[c][:] . h[p][:] + b2[c] ),  M=512, N=3136, K=2048
  k_gemm<2><<<dim3((HWPIX + 127)/128, DIM/128, NB), 256, 0, stream>>>(
      w2, h, b2, nullptr, x, gamma, out,
      DIM, HWPIX, HID, (long)DIM*HID, (long)HWPIX*HID, DIM);
}

// Round 4
// 1116.383 us; speedup vs baseline: 1.0568x; 1.0568x over previous
//
#include <hip/hip_runtime.h>

// ---- problem constants ----
#define NB    16
#define DIM   512
#define HH    56
#define WW    56
#define HWPIX 3136
#define HID   2048
#define NSTYLE 64
#define NLAT   8

typedef float f32x4 __attribute__((ext_vector_type(4)));
typedef __bf16 bf16x8 __attribute__((ext_vector_type(8)));
typedef unsigned short u16x8 __attribute__((ext_vector_type(8)));

__device__ __forceinline__ unsigned short f2bf(float f) {
  unsigned u = __float_as_uint(f);
  u += 0x7fffu + ((u >> 16) & 1u);   // round-to-nearest-even
  return (unsigned short)(u >> 16);
}

__device__ __forceinline__ void gload16(const void* g, void* l) {
  __builtin_amdgcn_global_load_lds((__attribute__((address_space(1))) void*)g,
                                   (__attribute__((address_space(3))) void*)l,
                                   16, 0, 0);
}

// tanh-form GELU: |err| vs exact < ~1e-3 on h, then ×w2×gamma(1e-6) -> negligible
__device__ __forceinline__ float fast_gelu(float x) {
  float u = 0.7978845608f * x * (1.0f + 0.044715f * x * x);
  float e = __expf(2.0f * u);          // inf-safe: e=inf -> t=1; e=0 -> t=-1
  float t = 1.0f - 2.0f / (1.0f + e);
  return 0.5f * x * (1.0f + t);
}

// ---- 1. small per-sample vectors ----
__global__ __launch_bounds__(256)
void k_small(const float* __restrict__ s,
             const float* __restrict__ dw_fc_w, const float* __restrict__ dw_fc_b,
             const float* __restrict__ dw_bfc_w, const float* __restrict__ dw_bfc_b,
             const float* __restrict__ p1_fc_w, const float* __restrict__ p1_fc_b,
             const float* __restrict__ p1_bfc_w, const float* __restrict__ p1_bfc_b,
             const float* __restrict__ p2_fc_w, const float* __restrict__ p2_fc_b,
             const float* __restrict__ p2_bfc_w, const float* __restrict__ p2_bfc_b,
             float* __restrict__ z_dw, float* __restrict__ z1, float* __restrict__ z2,
             float* __restrict__ b_dw, float* __restrict__ b1, float* __restrict__ b2) {
  int b = blockIdx.x, t = threadIdx.x;
  __shared__ float ls[NSTYLE];
  if (t < NSTYLE) ls[t] = s[b*NSTYLE + t];
  __syncthreads();
  if (t < NLAT) {
    float a0 = dw_fc_b[t], a1 = p1_fc_b[t], a2 = p2_fc_b[t];
    for (int j = 0; j < NSTYLE; ++j) {
      float sv = ls[j];
      a0 += sv * dw_fc_w[j*NLAT + t];
      a1 += sv * p1_fc_w[j*NLAT + t];
      a2 += sv * p2_fc_w[j*NLAT + t];
    }
    z_dw[b*NLAT + t] = a0; z1[b*NLAT + t] = a1; z2[b*NLAT + t] = a2;
  }
  for (int c = t; c < DIM; c += 256) {
    float a = dw_bfc_b[c], a2 = p2_bfc_b[c];
    for (int j = 0; j < NSTYLE; ++j) {
      float sv = ls[j];
      a  += sv * dw_bfc_w[j*DIM + c];
      a2 += sv * p2_bfc_w[j*DIM + c];
    }
    b_dw[b*DIM + c] = a; b2[b*DIM + c] = a2;
  }
  for (int c = t; c < HID; c += 256) {
    float a = p1_bfc_b[c];
    for (int j = 0; j < NSTYLE; ++j) a += ls[j] * p1_bfc_w[j*HID + c];
    b1[b*HID + c] = a;
  }
}

// ---- 2. depthwise kernel weights ----
__global__ __launch_bounds__(256)
void k_wdw(const float* __restrict__ z_dw, const float* __restrict__ dw_param,
           float* __restrict__ wdw) {
  int idx = blockIdx.x * 256 + threadIdx.x;
  if (idx >= NB*DIM) return;
  int b = idx >> 9, c = idx & 511;
  float z[NLAT];
#pragma unroll
  for (int ll = 0; ll < NLAT; ++ll) z[ll] = z_dw[b*NLAT + ll];
  for (int k = 0; k < 49; ++k) {
    float a = 0.f;
#pragma unroll
    for (int ll = 0; ll < NLAT; ++ll) a += z[ll] * dw_param[((long)ll*DIM + c)*49 + k];
    wdw[(long)idx*49 + k] = a;
  }
}

// ---- 3. generated GEMM weights (bf16, K-contiguous) ----
__global__ __launch_bounds__(256)
void k_wgen(const float* __restrict__ z, const float* __restrict__ param,
            unsigned short* __restrict__ out, long OI) {
  __shared__ float lz[NB*NLAT];
  if (threadIdx.x < NB*NLAT) lz[threadIdx.x] = z[threadIdx.x];
  __syncthreads();
  long e4 = ((long)blockIdx.x * 256 + threadIdx.x) * 4;
  if (e4 >= OI) return;
  float a[NB][4] = {};
#pragma unroll
  for (int ll = 0; ll < NLAT; ++ll) {
    float4 v = *(const float4*)(param + (long)ll*OI + e4);
#pragma unroll
    for (int b = 0; b < NB; ++b) {
      float zz = lz[b*NLAT + ll];
      a[b][0] += zz*v.x; a[b][1] += zz*v.y; a[b][2] += zz*v.z; a[b][3] += zz*v.w;
    }
  }
#pragma unroll
  for (int b = 0; b < NB; ++b) {
    ushort4 pk;
    pk.x = f2bf(a[b][0]); pk.y = f2bf(a[b][1]); pk.z = f2bf(a[b][2]); pk.w = f2bf(a[b][3]);
    *(ushort4*)(out + (long)b*OI + e4) = pk;
  }
}

// ---- 4. depthwise 7x7 conv, reflection pad on the fly ----
__global__ __launch_bounds__(64)
void k_dwconv(const float* __restrict__ x, const float* __restrict__ wdw,
              const float* __restrict__ bdw, float* __restrict__ y) {
  int bc = blockIdx.x;
  const float* xb = x + (long)bc * HWPIX;
  float* yb = y + (long)bc * HWPIX;
  int ox = threadIdx.x;
  bool act = ox < WW;
  int oxc = act ? ox : WW-1;
  int cj[7];
#pragma unroll
  for (int j = 0; j < 7; ++j) {
    int v = oxc + j - 3;
    v = v < 0 ? -v : (v > WW-1 ? 2*(WW-1) - v : v);
    cj[j] = v;
  }
  float wk[49];
#pragma unroll
  for (int k = 0; k < 49; ++k) wk[k] = wdw[(long)bc*49 + k];
  float bias = bdw[bc];
  float acc[7];
#pragma unroll
  for (int j = 0; j < 7; ++j) acc[j] = bias;
#pragma unroll 62
  for (int r = 0; r < HH + 6; ++r) {
    int sy = r - 3;
    sy = sy < 0 ? -sy : (sy > HH-1 ? 2*(HH-1) - sy : sy);
    const float* rowp = xb + sy*WW;
    float v[7];
#pragma unroll
    for (int j = 0; j < 7; ++j) v[j] = rowp[cj[j]];
#pragma unroll
    for (int dy = 0; dy < 7; ++dy) {
      int orow = r - dy;
      if (orow >= 0 && orow < HH) {
        float a = acc[orow % 7];
#pragma unroll
        for (int dx = 0; dx < 7; ++dx) a += v[dx] * wk[dy*7 + dx];
        acc[orow % 7] = a;
      }
    }
    if (r >= 6) {
      int orow = r - 6;
      if (act) yb[orow*WW + oxc] = acc[orow % 7];
      acc[orow % 7] = bias;
    }
  }
}

// ---- 5. LayerNorm: 32 pixels/block, 8 ch-groups, LDS-transposed coalesced stores ----
__global__ __launch_bounds__(256)
void k_ln(const float* __restrict__ y, const float* __restrict__ ln_w,
          const float* __restrict__ ln_b, unsigned short* __restrict__ xln) {
  __shared__ float red[2][8][32];
  __shared__ float stat[2][32];
  __shared__ unsigned short T[32][514];    // pad 514 -> stride 257 dwords (odd): conflict-free
  int b = blockIdx.y, p0 = blockIdx.x * 32;
  int t = threadIdx.x, cc = t >> 5, pc = t & 31;
  const float* yb = y + (long)b * DIM * HWPIX + p0 + pc;
  float vv[64];
  float s = 0.f, s2 = 0.f;
#pragma unroll
  for (int j = 0; j < 64; ++j) {
    float v = yb[(long)(cc*64 + j) * HWPIX];
    vv[j] = v; s += v; s2 += v*v;
  }
  red[0][cc][pc] = s; red[1][cc][pc] = s2;
  __syncthreads();
  if (t < 32) {
    float a = 0.f, a2 = 0.f;
#pragma unroll
    for (int k = 0; k < 8; ++k) { a += red[0][k][t]; a2 += red[1][k][t]; }
    float mean = a * (1.0f/DIM);
    float var  = a2 * (1.0f/DIM) - mean*mean;
    stat[0][t] = mean; stat[1][t] = rsqrtf(var + 1e-6f);
  }
  __syncthreads();
  float mean = stat[0][pc], rstd = stat[1][pc];
#pragma unroll
  for (int j8 = 0; j8 < 8; ++j8) {
    u16x8 pk;
#pragma unroll
    for (int jj = 0; jj < 8; ++jj) {
      int c = cc*64 + j8*8 + jj;
      pk[jj] = f2bf((vv[j8*8 + jj] - mean) * rstd * ln_w[c] + ln_b[c]);
    }
    *(u16x8*)&T[pc][cc*64 + j8*8] = pk;
  }
  __syncthreads();
  unsigned short* dst = xln + ((long)b * HWPIX + p0) * DIM;
#pragma unroll
  for (int r = 0; r < 8; ++r) {
    int idx = r*256 + t;
    int px = idx >> 6, cl = idx & 63;          // one wave = one pixel row: 64x16B = 1KB coalesced
    u16x8 v = *(u16x8*)&T[px][cl*8];
    *(u16x8*)(dst + (long)px*DIM + cl*8) = v;
  }
}

// ---- 6. MFMA GEMM, 128x128 tile, BK=64, T2 XOR-swizzled LDS, gload_lds staging ----
// LDS layout [128 rows][8 chunks of 16B]; LDS chunk kc holds global chunk (kc ^ (row&7)).
// Staging: linear dest + inverse-swizzled global source; reads XOR back (rule #21).
template<int MODE>
__global__ __launch_bounds__(256)
void k_gemm(const unsigned short* __restrict__ A, const unsigned short* __restrict__ Bt,
            const float* __restrict__ bias,
            unsigned short* __restrict__ hout,
            const float* __restrict__ xin, const float* __restrict__ gamma,
            float* __restrict__ fout,
            int M, int N, int Kd, long sA, long sBt, int sBias) {
  __shared__ unsigned short lsA[128*64];
  __shared__ unsigned short lsB[128*64];
  int bz = blockIdx.z;
  int row0 = blockIdx.y * 128, col0 = blockIdx.x * 128;
  int t = threadIdx.x, l = t & 63;
  const unsigned short* Ab  = A  + (long)bz * sA;
  const unsigned short* Btb = Bt + (long)bz * sBt;
  // staging: chunk idx = j*256 + t; r = idx>>3 = j*32 + (t>>3); kc = t&7 (same for all j)
  int rbase = t >> 3;
  int kcs   = (t & 7) ^ (rbase & 7);           // inverse-swizzled source chunk
  const unsigned short* ga = Ab  + (long)(row0 + rbase) * Kd + kcs * 8;
  const unsigned short* gb = Btb + (long)(col0 + rbase) * Kd + kcs * 8;
  char* la = (char*)lsA + t * 16;              // linear dest: base + lane*16
  char* lb = (char*)lsB + t * 16;
  int w = t >> 6, wr = w >> 1, wc = w & 1;
  int rr = l & 15;
  // fragment read addresses (bytes): row*128 + (kchunk*16 ^ ((row&7)<<4))
  int swz = (rr & 7) << 4;
  int rowA[4], rowB[4];
#pragma unroll
  for (int m = 0; m < 4; ++m) rowA[m] = (wr*64 + m*16 + rr) * 128;
#pragma unroll
  for (int n = 0; n < 4; ++n) rowB[n] = (wc*64 + n*16 + rr) * 128;
  int koff[2];
#pragma unroll
  for (int ks = 0; ks < 2; ++ks) koff[ks] = ((ks*64 + (l >> 4)*16) ^ swz);
  f32x4 acc[4][4] = {};
  int nk = Kd >> 6;
  long r32K = (long)32 * Kd;                   // 32 rows stride (elements)
  for (int kk = 0; kk < nk; ++kk) {
#pragma unroll
    for (int j = 0; j < 4; ++j) gload16(ga + j*r32K, la + j*4096);
#pragma unroll
    for (int j = 0; j < 4; ++j) gload16(gb + j*r32K, lb + j*4096);
    ga += 64; gb += 64;
    __syncthreads();                           // drains vmcnt(0) (compiler-inserted)
#pragma unroll
    for (int ks = 0; ks < 2; ++ks) {
      bf16x8 af[4], bfr[4];
#pragma unroll
      for (int m = 0; m < 4; ++m)
        af[m] = *(const bf16x8*)((char*)lsA + rowA[m] + koff[ks]);
#pragma unroll
      for (int n = 0; n < 4; ++n)
        bfr[n] = *(const bf16x8*)((char*)lsB + rowB[n] + koff[ks]);
#pragma unroll
      for (int m = 0; m < 4; ++m)
#pragma unroll
        for (int n = 0; n < 4; ++n)
          acc[m][n] = __builtin_amdgcn_mfma_f32_16x16x32_bf16(af[m], bfr[n], acc[m][n], 0, 0, 0);
    }
    __syncthreads();
  }
  long ob = (long)bz * M * N;
  const float* biasb = bias + (long)bz * sBias;
#pragma unroll
  for (int m = 0; m < 4; ++m) {
#pragma unroll
    for (int n = 0; n < 4; ++n) {
      int col = col0 + wc*64 + n*16 + rr;
#pragma unroll
      for (int j = 0; j < 4; ++j) {
        int row = row0 + wr*64 + m*16 + (l >> 4)*4 + j;   // C/D: col=lane&15, row=(lane>>4)*4+reg
        float v = acc[m][n][j];
        if constexpr (MODE == 1) {
          if (row < M) {
            v += biasb[col];
            v = fast_gelu(v);
            hout[ob + (long)row * N + col] = f2bf(v);
          }
        } else {
          if (col < N) {
            v = (v + biasb[row]) * gamma[row] + xin[ob + (long)row * N + col];
            fout[ob + (long)row * N + col] = v;
          }
        }
      }
    }
  }
}

extern "C" void kernel_launch(void* const* d_in, const int* in_sizes, int n_in,
                              void* d_out, int out_size, void* d_ws, size_t ws_size,
                              hipStream_t stream) {
  (void)in_sizes; (void)n_in; (void)out_size; (void)ws_size;
  const float* x         = (const float*)d_in[0];
  const float* s         = (const float*)d_in[1];
  const float* dw_fc_w   = (const float*)d_in[2];
  const float* dw_fc_b   = (const float*)d_in[3];
  const float* dw_param  = (const float*)d_in[4];
  const float* dw_bfc_w  = (const float*)d_in[5];
  const float* dw_bfc_b  = (const float*)d_in[6];
  const float* ln_w      = (const float*)d_in[7];
  const float* ln_b      = (const float*)d_in[8];
  const float* pw1_fc_w  = (const float*)d_in[9];
  const float* pw1_fc_b  = (const float*)d_in[10];
  const float* pw1_param = (const float*)d_in[11];
  const float* pw1_bfc_w = (const float*)d_in[12];
  const float* pw1_bfc_b = (const float*)d_in[13];
  const float* pw2_fc_w  = (const float*)d_in[14];
  const float* pw2_fc_b  = (const float*)d_in[15];
  const float* pw2_param = (const float*)d_in[16];
  const float* pw2_bfc_w = (const float*)d_in[17];
  const float* pw2_bfc_b = (const float*)d_in[18];
  const float* gamma     = (const float*)d_in[19];
  float* out = (float*)d_out;

  char* ws = (char*)d_ws;
  size_t off = 0;
  auto alloc = [&](size_t bytes) {
    void* p = ws + off;
    off += (bytes + 255) & ~(size_t)255;
    return p;
  };
  float* z_dw = (float*)alloc(NB*NLAT*4);
  float* z1   = (float*)alloc(NB*NLAT*4);
  float* z2   = (float*)alloc(NB*NLAT*4);
  float* b_dw = (float*)alloc((size_t)NB*DIM*4);
  float* b2   = (float*)alloc((size_t)NB*DIM*4);
  float* b1   = (float*)alloc((size_t)NB*HID*4);
  float* wdw  = (float*)alloc((size_t)NB*DIM*49*4);
  unsigned short* w1  = (unsigned short*)alloc((size_t)NB*HID*DIM*2);
  unsigned short* w2  = (unsigned short*)alloc((size_t)NB*DIM*HID*2);
  unsigned short* xln = (unsigned short*)alloc((size_t)NB*HWPIX*DIM*2 + 131072);  // + edge-tile pad
  unsigned short* h   = (unsigned short*)alloc((size_t)NB*HWPIX*HID*2 + 524288);  // + edge-tile pad

  float* y = out;  // reuse d_out as dwconv scratch; fully overwritten by final GEMM

  k_small<<<NB, 256, 0, stream>>>(s, dw_fc_w, dw_fc_b, dw_bfc_w, dw_bfc_b,
                                  pw1_fc_w, pw1_fc_b, pw1_bfc_w, pw1_bfc_b,
                                  pw2_fc_w, pw2_fc_b, pw2_bfc_w, pw2_bfc_b,
                                  z_dw, z1, z2, b_dw, b1, b2);
  k_wdw<<<(NB*DIM + 255)/256, 256, 0, stream>>>(z_dw, dw_param, wdw);
  {
    long OI = (long)HID * DIM;                  // 1,048,576
    int blocks = (int)(OI / 4 / 256);           // 1024, exact
    k_wgen<<<blocks, 256, 0, stream>>>(z1, pw1_param, w1, OI);
    k_wgen<<<blocks, 256, 0, stream>>>(z2, pw2_param, w2, OI);
  }
  k_dwconv<<<NB*DIM, 64, 0, stream>>>(x, wdw, b_dw, y);
  k_ln<<<dim3(HWPIX/32, NB), 256, 0, stream>>>(y, ln_w, ln_b, xln);

  // GEMM1: h[p][o] = GELU( xln[p][:] . w1[o][:] + b1[o] ),  M=3136, N=2048, K=512
  k_gemm<1><<<dim3(HID/128, (HWPIX + 127)/128, NB), 256, 0, stream>>>(
      xln, w1, b1, h, nullptr, nullptr, nullptr,
      HWPIX, HID, DIM, (long)HWPIX*DIM, (long)HID*DIM, HID);

  // GEMM2: out[c][p] = xin + gamma[c] * ( w2[c][:] . h[p][:] + b2[c] ),  M=512, N=3136, K=2048
  k_gemm<2><<<dim3((HWPIX + 127)/128, DIM/128, NB), 256, 0, stream>>>(
      w2, h, b2, nullptr, x, gamma, out,
      DIM, HWPIX, HID, (long)DIM*HID, (long)HWPIX*HID, DIM);
}